// Round 1
// baseline (1272.303 us; speedup 1.0000x reference)
//
#include <hip/hip_runtime.h>

// MaskedMHA: fused QKV GEMM + GQA flash attention, MI355X gfx950.
// B=4, Q=1024, P=1024, S=2048, H=32, KV=8, D=128, HID=4096, N_qkv=6144.
// ws layout (needs 144 MiB):
//   Xb  [4096][4096] bf16 @ 0          (32 MiB)
//   Wb  [6144][4096] bf16 @ 33554432   (48 MiB)
//   Qb  [B][H][Q][D] bf16 @ 83886080   (32 MiB)
//   Kb  [B][KV][S][D] bf16 @ 117440512 (16 MiB)
//   Vtb [B][KV][D][S] bf16 @ 134217728 (16 MiB)  (V pre-transposed)
// d_out: out fp32 [B][H][Q][D] | k fp32 [B][S][KV][D] | v fp32 [B][S][KV][D]

typedef __attribute__((ext_vector_type(4))) float f32x4;
typedef __attribute__((ext_vector_type(8))) short bf16x8;
typedef __attribute__((ext_vector_type(8))) unsigned short u16x8;
typedef __attribute__((ext_vector_type(4))) unsigned short u16x4;

#define LOG2E 1.4426950408889634f
#define SCALE 0.08838834764831843f  /* 1/sqrt(128) */

__device__ __forceinline__ unsigned short f2bf(float f) {
  unsigned int u = __builtin_bit_cast(unsigned int, f);
  u = (u + 0x7FFFu + ((u >> 16) & 1u)) >> 16;  // RNE
  return (unsigned short)u;
}

// async global->LDS, 16B per lane. LDS dest is wave-uniform base + lane*16.
__device__ __forceinline__ void async16(void* lds, const void* g) {
  __builtin_amdgcn_global_load_lds(
      (const __attribute__((address_space(1))) unsigned int*)(unsigned long long)g,
      (__attribute__((address_space(3))) unsigned int*)(unsigned int)(unsigned long long)lds,
      16, 0, 0);
}

// ---------------- converters ----------------

__global__ __launch_bounds__(256) void conv_bf16_kernel(
    const float* __restrict__ in, unsigned short* __restrict__ out, int n8) {
  int i = blockIdx.x * 256 + threadIdx.x;
  if (i >= n8) return;
  const f32x4* in4 = (const f32x4*)in;
  f32x4 a = in4[i * 2], c = in4[i * 2 + 1];
  u16x8 o;
#pragma unroll
  for (int j = 0; j < 4; j++) { o[j] = f2bf(a[j]); o[4 + j] = f2bf(c[j]); }
  *(u16x8*)(out + i * 8) = o;
}

// key_cache [B,1024,KV,D] -> Kb bf16 [B,KV,2048,D] (s<1024) + outK fp32 copy
__global__ __launch_bounds__(256) void conv_k_kernel(
    const float* __restrict__ kc, unsigned short* __restrict__ Kb, float* __restrict__ outK) {
  int i = blockIdx.x * 256 + threadIdx.x;  // 524288 total (8 elems each)
  int d8 = i & 15, kv = (i >> 4) & 7, s = (i >> 7) & 1023, b = i >> 17;
  const float* src = kc + (((b * 1024 + s) * 8 + kv) * 128) + d8 * 8;
  f32x4 v0 = ((const f32x4*)src)[0], v1 = ((const f32x4*)src)[1];
  float* ko = outK + (((b * 2048 + s) * 8 + kv) * 128) + d8 * 8;
  ((f32x4*)ko)[0] = v0; ((f32x4*)ko)[1] = v1;
  u16x8 o;
#pragma unroll
  for (int j = 0; j < 4; j++) { o[j] = f2bf(v0[j]); o[4 + j] = f2bf(v1[j]); }
  *(u16x8*)(Kb + ((b * 8 + kv) * 2048 + s) * 128 + d8 * 8) = o;
}

// value_cache [B,1024,KV,D] -> Vtb bf16 [B,KV,D,2048] (transpose, s<1024) + outV fp32 copy
__global__ __launch_bounds__(256) void conv_v_kernel(
    const float* __restrict__ vc, unsigned short* __restrict__ Vtb, float* __restrict__ outV) {
  __shared__ unsigned short t[32][33];
  const int bid = blockIdx.x;                 // 4096 blocks
  const int s0 = (bid & 31) * 32;
  const int d0 = ((bid >> 5) & 3) * 32;
  const int kv = (bid >> 7) & 7;
  const int b = bid >> 10;
  const int tx = threadIdx.x & 31, ty = threadIdx.x >> 5;
#pragma unroll
  for (int p = 0; p < 4; p++) {
    const int si = p * 8 + ty;
    float v = vc[(((b * 1024 + s0 + si) * 8 + kv) * 128) + d0 + tx];
    outV[(((b * 2048 + s0 + si) * 8 + kv) * 128) + d0 + tx] = v;
    t[tx][si] = f2bf(v);
  }
  __syncthreads();
#pragma unroll
  for (int p = 0; p < 4; p++) {
    const int dr = p * 8 + ty;
    Vtb[((b * 8 + kv) * 128 + d0 + dr) * 2048 + s0 + tx] = t[dr][tx];
  }
}

// ---------------- QKV GEMM ----------------
// C[m,n] = sum_k Xb[m,k]*Wb[n,k] + bias[n]; 128x128 tile, BK=32, 4 waves.
// LDS rows 64B = 4 x 16B chunks; chunk c stored at c ^ ((row>>1)&3) (XOR involution,
// applied to global src on staging and to ds_read addr on reads).
__global__ __launch_bounds__(256) void qkv_gemm_kernel(
    const unsigned short* __restrict__ Xb, const unsigned short* __restrict__ Wb,
    const float* __restrict__ bias,
    unsigned short* __restrict__ Qb, unsigned short* __restrict__ Kb,
    unsigned short* __restrict__ Vtb, float* __restrict__ outK, float* __restrict__ outV) {
  const int K = 4096;
  __shared__ unsigned short As[4096];
  __shared__ unsigned short Bs[4096];
  const int tid = threadIdx.x;
  const int wave = tid >> 6, lane = tid & 63;
  const int g = lane >> 4, l15 = lane & 15;
  const int bm = blockIdx.x, bn = blockIdx.y;
  const int wr = wave >> 1, wc = wave & 1;

  // staging: 512 x 16B slots per matrix; slot -> row=slot>>2, chunk'=slot&3
  const int slot0 = wave * 128 + lane, slot1 = slot0 + 64;
  const int r0 = slot0 >> 2, c0 = (slot0 & 3) ^ ((r0 >> 1) & 3);
  const int r1 = slot1 >> 2, c1 = (slot1 & 3) ^ ((r1 >> 1) & 3);

  const unsigned short* Ab = Xb + bm * 128 * K;
  const unsigned short* Bb = Wb + bn * 128 * K;
  const unsigned short* gA0 = Ab + r0 * K + c0 * 8;
  const unsigned short* gA1 = Ab + r1 * K + c1 * 8;
  const unsigned short* gB0 = Bb + r0 * K + c0 * 8;
  const unsigned short* gB1 = Bb + r1 * K + c1 * 8;
  unsigned short* ldsA0 = As + wave * 1024;
  unsigned short* ldsA1 = As + wave * 1024 + 512;
  unsigned short* ldsB0 = Bs + wave * 1024;
  unsigned short* ldsB1 = Bs + wave * 1024 + 512;

  f32x4 acc[4][4] = {};

  for (int k0 = 0; k0 < K; k0 += 32) {
    async16(ldsA0, gA0 + k0);
    async16(ldsA1, gA1 + k0);
    async16(ldsB0, gB0 + k0);
    async16(ldsB1, gB1 + k0);
    __syncthreads();  // drains vmcnt -> LDS tiles ready
    bf16x8 af[4], bfr[4];
#pragma unroll
    for (int i = 0; i < 4; i++) {
      const int rm = wr * 64 + i * 16 + l15;
      af[i] = *(const bf16x8*)(As + rm * 32 + ((g ^ ((rm >> 1) & 3)) * 8));
      const int rn = wc * 64 + i * 16 + l15;
      bfr[i] = *(const bf16x8*)(Bs + rn * 32 + ((g ^ ((rn >> 1) & 3)) * 8));
    }
#pragma unroll
    for (int i = 0; i < 4; i++)
#pragma unroll
      for (int j = 0; j < 4; j++)
        acc[i][j] = __builtin_amdgcn_mfma_f32_16x16x32_bf16(af[i], bfr[j], acc[i][j], 0, 0, 0);
    __syncthreads();  // all reads done before next staging
  }

  // epilogue: C/D layout col=lane&15, row=(lane>>4)*4+reg. Block's n-range is uniform.
  const int b = bm >> 3;
  const int qbase = (bm & 7) << 7;
  if (bn < 32) {  // q heads -> Qb bf16
#pragma unroll
    for (int j = 0; j < 4; j++) {
      const int n = bn * 128 + wc * 64 + j * 16 + l15;
      const float bv = bias[n];
      const int h = n >> 7, d = n & 127;
#pragma unroll
      for (int i = 0; i < 4; i++) {
        const int q0 = qbase + wr * 64 + i * 16 + g * 4;
        unsigned short* dst = Qb + (((b * 32 + h) * 1024 + q0) * 128 + d);
#pragma unroll
        for (int r = 0; r < 4; r++) dst[r * 128] = f2bf(acc[i][j][r] + bv);
      }
    }
  } else if (bn < 40) {  // k_new -> outK fp32 + Kb bf16
#pragma unroll
    for (int j = 0; j < 4; j++) {
      const int n = bn * 128 + wc * 64 + j * 16 + l15;
      const float bv = bias[n];
      const int n2 = n - 4096, kv = n2 >> 7, d = n2 & 127;
#pragma unroll
      for (int i = 0; i < 4; i++) {
        const int q0 = qbase + wr * 64 + i * 16 + g * 4;
        float* ko = outK + (((b * 2048 + 1024 + q0) * 8 + kv) * 128 + d);
        unsigned short* kb = Kb + (((b * 8 + kv) * 2048 + 1024 + q0) * 128 + d);
#pragma unroll
        for (int r = 0; r < 4; r++) {
          float v = acc[i][j][r] + bv;
          ko[r * 1024] = v;
          kb[r * 128] = f2bf(v);
        }
      }
    }
  } else {  // v_new -> outV fp32 + Vtb bf16 (transposed: 4 consecutive q pack to 8B)
#pragma unroll
    for (int j = 0; j < 4; j++) {
      const int n = bn * 128 + wc * 64 + j * 16 + l15;
      const float bv = bias[n];
      const int n2 = n - 5120, kv = n2 >> 7, d = n2 & 127;
#pragma unroll
      for (int i = 0; i < 4; i++) {
        const int q0 = qbase + wr * 64 + i * 16 + g * 4;
        float* vo = outV + (((b * 2048 + 1024 + q0) * 8 + kv) * 128 + d);
        u16x4 pk;
#pragma unroll
        for (int r = 0; r < 4; r++) {
          float v = acc[i][j][r] + bv;
          vo[r * 1024] = v;
          pk[r] = f2bf(v);
        }
        *(u16x4*)(Vtb + ((b * 8 + kv) * 128 + d) * 2048 + 1024 + q0) = pk;
      }
    }
  }
}

// ---------------- flash attention ----------------
// grid (qt=8, h=32, b=4); 4 waves x 32 q-rows = 128 q/block; S-tiles of 32.
// K LDS [32 s][128 d]: rows 256B = 16 chunks, chunk c at c^(s&7).
// V LDS [128 d][32 s] (from pre-transposed Vtb): rows 64B = 4 chunks, c^( (d>>1)&3 ).
// P LDS per-wave [32 q][32 s]: rows 64B = 4 chunks, c^((q>>1)&3).
__global__ __launch_bounds__(256) void attn_kernel(
    const unsigned short* __restrict__ Qb, const unsigned short* __restrict__ Kb,
    const unsigned short* __restrict__ Vtb, const float* __restrict__ mask,
    float* __restrict__ outO) {
  __shared__ unsigned short Ks[4096];
  __shared__ unsigned short Vs[4096];
  __shared__ unsigned short Ps[4096];

  const int tid = threadIdx.x, wave = tid >> 6, lane = tid & 63;
  const int g = lane >> 4, l15 = lane & 15;
  const int qt = blockIdx.x, h = blockIdx.y, b = blockIdx.z;
  const int kvh = h >> 2;  // GQA: head h uses kv head h/4

  const unsigned short* Kg = Kb + (b * 8 + kvh) * 2048 * 128;
  const unsigned short* Vg = Vtb + (b * 8 + kvh) * 128 * 2048;
  const int qg0 = qt * 128 + wave * 32;

  // Q fragments held in registers: qf[i][kg], rows qg0+i*16+l15, k = kg*32+g*8..+7
  bf16x8 qf[2][4];
#pragma unroll
  for (int i = 0; i < 2; i++) {
    const unsigned short* qrow = Qb + (((b * 32 + h) * 1024) + qg0 + i * 16 + l15) * 128;
#pragma unroll
    for (int kg = 0; kg < 4; kg++) qf[i][kg] = *(const bf16x8*)(qrow + kg * 32 + g * 8);
  }

  f32x4 acc_o[2][8] = {};
  float m_run[2][4], l_run[2][4];
#pragma unroll
  for (int i = 0; i < 2; i++)
#pragma unroll
    for (int r = 0; r < 4; r++) { m_run[i][r] = -1e30f; l_run[i][r] = 0.f; }

  // staging address precompute (2 slots per matrix per thread)
  const int slot0 = wave * 128 + lane, slot1 = slot0 + 64;
  const int kr0 = slot0 >> 4, kc0 = (slot0 & 15) ^ (kr0 & 7);
  const int kr1 = slot1 >> 4, kc1 = (slot1 & 15) ^ (kr1 & 7);
  const int vr0 = slot0 >> 2, vc0 = (slot0 & 3) ^ ((vr0 >> 1) & 3);
  const int vr1 = slot1 >> 2, vc1 = (slot1 & 3) ^ ((vr1 >> 1) & 3);
  unsigned short* ldsK0 = Ks + wave * 1024;
  unsigned short* ldsK1 = Ks + wave * 1024 + 512;
  unsigned short* ldsV0 = Vs + wave * 1024;
  unsigned short* ldsV1 = Vs + wave * 1024 + 512;
  unsigned short* Pw = Ps + wave * 1024;  // wave-private P slab

  const float* maskB = mask + (b * 1024 + qg0) * 2048;

  for (int s0 = 0; s0 < 2048; s0 += 32) {
    __syncthreads();  // prev tile fully consumed
    async16(ldsK0, Kg + (s0 + kr0) * 128 + kc0 * 8);
    async16(ldsK1, Kg + (s0 + kr1) * 128 + kc1 * 8);
    async16(ldsV0, Vg + vr0 * 2048 + s0 + vc0 * 8);
    async16(ldsV1, Vg + vr1 * 2048 + s0 + vc1 * 8);
    __syncthreads();  // staging complete

    // QK^T: A=Q, B=K^T; 2 q-subtiles x 2 s-subtiles x 4 k-groups
    bf16x8 kf[2][4];
#pragma unroll
    for (int sc = 0; sc < 2; sc++) {
      const int srow = sc * 16 + l15;
#pragma unroll
      for (int kg = 0; kg < 4; kg++)
        kf[sc][kg] = *(const bf16x8*)(Ks + srow * 128 + (((kg * 4 + g) ^ (srow & 7)) * 8));
    }
    f32x4 scv[2][2];
#pragma unroll
    for (int i = 0; i < 2; i++)
#pragma unroll
      for (int sc = 0; sc < 2; sc++) {
        f32x4 a = {};
#pragma unroll
        for (int kg = 0; kg < 4; kg++)
          a = __builtin_amdgcn_mfma_f32_16x16x32_bf16(qf[i][kg], kf[sc][kg], a, 0, 0, 0);
        scv[i][sc] = a;
      }

    // online softmax; score row q = i*16+g*4+r, col s = sc*16+l15
    float alpha[2][4];
#pragma unroll
    for (int i = 0; i < 2; i++)
#pragma unroll
      for (int r = 0; r < 4; r++) {
        const int ql = i * 16 + g * 4 + r;
        const float* mrow = maskB + ql * 2048 + s0;
        float x0 = scv[i][0][r] * SCALE + mrow[l15];
        float x1 = scv[i][1][r] * SCALE + mrow[16 + l15];
        float mx = fmaxf(x0, x1);
        mx = fmaxf(mx, __shfl_xor(mx, 1));
        mx = fmaxf(mx, __shfl_xor(mx, 2));
        mx = fmaxf(mx, __shfl_xor(mx, 4));
        mx = fmaxf(mx, __shfl_xor(mx, 8));
        const float mnew = fmaxf(m_run[i][r], mx);
        const float al = exp2f((m_run[i][r] - mnew) * LOG2E);
        m_run[i][r] = mnew;
        const float p0 = exp2f((x0 - mnew) * LOG2E);
        const float p1 = exp2f((x1 - mnew) * LOG2E);
        float ps = p0 + p1;
        ps += __shfl_xor(ps, 1);
        ps += __shfl_xor(ps, 2);
        ps += __shfl_xor(ps, 4);
        ps += __shfl_xor(ps, 8);
        l_run[i][r] = l_run[i][r] * al + ps;
        alpha[i][r] = al;
        // bounce P through wave-private LDS (layout transpose for PV A-operand)
        const int swz = (ql >> 1) & 3;
        Pw[ql * 32 + (((l15 >> 3) ^ swz) * 8) + (l15 & 7)] = f2bf(p0);
        Pw[ql * 32 + (((2 + (l15 >> 3)) ^ swz) * 8) + (l15 & 7)] = f2bf(p1);
      }

    // rescale O by alpha (row-matched: acc_o row = i*16+g*4+r)
#pragma unroll
    for (int i = 0; i < 2; i++)
#pragma unroll
      for (int ds = 0; ds < 8; ds++)
#pragma unroll
        for (int r = 0; r < 4; r++) acc_o[i][ds][r] *= alpha[i][r];

    // PV: A=P (q x s), B=V^T (s x d) from Vs
    bf16x8 pf[2];
#pragma unroll
    for (int i = 0; i < 2; i++) {
      const int ql = i * 16 + l15;
      pf[i] = *(const bf16x8*)(Pw + ql * 32 + ((g ^ ((ql >> 1) & 3)) * 8));
    }
#pragma unroll
    for (int ds = 0; ds < 8; ds++) {
      const int dr = ds * 16 + l15;
      bf16x8 vf = *(const bf16x8*)(Vs + dr * 32 + ((g ^ ((dr >> 1) & 3)) * 8));
#pragma unroll
      for (int i = 0; i < 2; i++)
        acc_o[i][ds] = __builtin_amdgcn_mfma_f32_16x16x32_bf16(pf[i], vf, acc_o[i][ds], 0, 0, 0);
    }
  }

  // epilogue: out[b][h][q][d] fp32
#pragma unroll
  for (int i = 0; i < 2; i++)
#pragma unroll
    for (int r = 0; r < 4; r++) {
      const float inv = 1.0f / l_run[i][r];
      const int qgl = qg0 + i * 16 + g * 4 + r;
      float* orow = outO + (((b * 32 + h) * 1024) + qgl) * 128 + l15;
#pragma unroll
      for (int ds = 0; ds < 8; ds++) orow[ds * 16] = acc_o[i][ds][r] * inv;
    }
}

// ---------------- launcher ----------------

extern "C" void kernel_launch(void* const* d_in, const int* in_sizes, int n_in,
                              void* d_out, int out_size, void* d_ws, size_t ws_size,
                              hipStream_t stream) {
  const float* input_t = (const float*)d_in[0];
  const float* key_cache = (const float*)d_in[1];
  const float* value_cache = (const float*)d_in[2];
  // d_in[3] = max_position (unused by reference), d_in[5] = beam_idx (unused)
  const float* attn_mask = (const float*)d_in[4];
  const float* qkv_w = (const float*)d_in[6];
  const float* qkv_b = (const float*)d_in[7];

  float* out = (float*)d_out;                 // [4][32][1024][128]
  float* outK = out + 16777216;               // [4][2048][8][128]
  float* outV = outK + 8388608;               // [4][2048][8][128]

  char* ws = (char*)d_ws;                     // needs 150994944 B
  unsigned short* Xb = (unsigned short*)ws;
  unsigned short* Wb = (unsigned short*)(ws + 33554432);
  unsigned short* Qb = (unsigned short*)(ws + 83886080);
  unsigned short* Kb = (unsigned short*)(ws + 117440512);
  unsigned short* Vtb = (unsigned short*)(ws + 134217728);

  hipLaunchKernelGGL(conv_bf16_kernel, dim3(8192), dim3(256), 0, stream, input_t, Xb, 2097152);
  hipLaunchKernelGGL(conv_bf16_kernel, dim3(12288), dim3(256), 0, stream, qkv_w, Wb, 3145728);
  hipLaunchKernelGGL(conv_k_kernel, dim3(2048), dim3(256), 0, stream, key_cache, Kb, outK);
  hipLaunchKernelGGL(conv_v_kernel, dim3(4096), dim3(256), 0, stream, value_cache, Vtb, outV);
  hipLaunchKernelGGL(qkv_gemm_kernel, dim3(32, 48), dim3(256), 0, stream,
                     Xb, Wb, qkv_b, Qb, Kb, Vtb, outK, outV);
  hipLaunchKernelGGL(attn_kernel, dim3(8, 32, 4), dim3(256), 0, stream,
                     Qb, Kb, Vtb, attn_mask, out);
}

// Round 3
// 1111.535 us; speedup vs baseline: 1.1446x; 1.1446x over previous
//
#include <hip/hip_runtime.h>

// MaskedMHA: fused QKV GEMM + GQA flash attention, MI355X gfx950.
// B=4, Q=1024, P=1024, S=2048, H=32, KV=8, D=128, HID=4096, N_qkv=6144.
// ws layout (needs 144 MiB):
//   Xb  [4096][4096] bf16 @ 0          (32 MiB)
//   Wb  [6144][4096] bf16 @ 33554432   (48 MiB)
//   Qb  [B][H][Q][D] bf16 @ 83886080   (32 MiB)
//   Kb  [B][KV][S][D] bf16 @ 117440512 (16 MiB)
//   Vtb [B][KV][D][S] bf16 @ 134217728 (16 MiB)  (V pre-transposed)
// d_out: out fp32 [B][H][Q][D] | k fp32 [B][S][KV][D] | v fp32 [B][S][KV][D]

typedef __attribute__((ext_vector_type(4))) float f32x4;
typedef __attribute__((ext_vector_type(8))) short bf16x8;
typedef __attribute__((ext_vector_type(8))) unsigned short u16x8;
typedef __attribute__((ext_vector_type(4))) unsigned short u16x4;

#define LOG2E 1.4426950408889634f
#define SCALE 0.08838834764831843f   /* 1/sqrt(128) */
#define SCALE2 0.12751649736689687f  /* SCALE*LOG2E */

__device__ __forceinline__ unsigned short f2bf(float f) {
  unsigned int u = __builtin_bit_cast(unsigned int, f);
  u = (u + 0x7FFFu + ((u >> 16) & 1u)) >> 16;  // RNE
  return (unsigned short)u;
}

// async global->LDS, 16B per lane. LDS dest is wave-uniform base + lane*16.
__device__ __forceinline__ void async16(void* lds, const void* g) {
  __builtin_amdgcn_global_load_lds(
      (const __attribute__((address_space(1))) unsigned int*)(unsigned long long)g,
      (__attribute__((address_space(3))) unsigned int*)(unsigned int)(unsigned long long)lds,
      16, 0, 0);
}

// ---------------- converters ----------------

__global__ __launch_bounds__(256) void conv_bf16_kernel(
    const float* __restrict__ in, unsigned short* __restrict__ out, int n8) {
  int i = blockIdx.x * 256 + threadIdx.x;
  if (i >= n8) return;
  const f32x4* in4 = (const f32x4*)in;
  f32x4 a = in4[i * 2], c = in4[i * 2 + 1];
  u16x8 o;
#pragma unroll
  for (int j = 0; j < 4; j++) { o[j] = f2bf(a[j]); o[4 + j] = f2bf(c[j]); }
  *(u16x8*)(out + i * 8) = o;
}

// key_cache [B,1024,KV,D] -> Kb bf16 [B,KV,2048,D] (s<1024) + outK fp32 copy
__global__ __launch_bounds__(256) void conv_k_kernel(
    const float* __restrict__ kc, unsigned short* __restrict__ Kb, float* __restrict__ outK) {
  int i = blockIdx.x * 256 + threadIdx.x;  // 524288 total (8 elems each)
  int d8 = i & 15, kv = (i >> 4) & 7, s = (i >> 7) & 1023, b = i >> 17;
  const float* src = kc + (((b * 1024 + s) * 8 + kv) * 128) + d8 * 8;
  f32x4 v0 = ((const f32x4*)src)[0], v1 = ((const f32x4*)src)[1];
  float* ko = outK + (((b * 2048 + s) * 8 + kv) * 128) + d8 * 8;
  ((f32x4*)ko)[0] = v0; ((f32x4*)ko)[1] = v1;
  u16x8 o;
#pragma unroll
  for (int j = 0; j < 4; j++) { o[j] = f2bf(v0[j]); o[4 + j] = f2bf(v1[j]); }
  *(u16x8*)(Kb + ((b * 8 + kv) * 2048 + s) * 128 + d8 * 8) = o;
}

// value_cache [B,1024,KV,D] -> Vtb bf16 [B,KV,D,2048] (transpose, s<1024) + outV fp32 copy
__global__ __launch_bounds__(256) void conv_v_kernel(
    const float* __restrict__ vc, unsigned short* __restrict__ Vtb, float* __restrict__ outV) {
  __shared__ unsigned short t[32][33];
  const int bid = blockIdx.x;                 // 4096 blocks
  const int s0 = (bid & 31) * 32;
  const int d0 = ((bid >> 5) & 3) * 32;
  const int kv = (bid >> 7) & 7;
  const int b = bid >> 10;
  const int tx = threadIdx.x & 31, ty = threadIdx.x >> 5;
#pragma unroll
  for (int p = 0; p < 4; p++) {
    const int si = p * 8 + ty;
    float v = vc[(((b * 1024 + s0 + si) * 8 + kv) * 128) + d0 + tx];
    outV[(((b * 2048 + s0 + si) * 8 + kv) * 128) + d0 + tx] = v;
    t[tx][si] = f2bf(v);
  }
  __syncthreads();
#pragma unroll
  for (int p = 0; p < 4; p++) {
    const int dr = p * 8 + ty;
    Vtb[((b * 8 + kv) * 128 + d0 + dr) * 2048 + s0 + tx] = t[dr][tx];
  }
}

// ---------------- QKV GEMM ----------------
// C[m,n] = sum_k Xb[m,k]*Wb[n,k] + bias[n]; 128x128 tile, BK=32, 4 waves.
// LDS rows 64B = 4 x 16B chunks; chunk c stored at c ^ ((row>>1)&3).
__global__ __launch_bounds__(256) void qkv_gemm_kernel(
    const unsigned short* __restrict__ Xb, const unsigned short* __restrict__ Wb,
    const float* __restrict__ bias,
    unsigned short* __restrict__ Qb, unsigned short* __restrict__ Kb,
    unsigned short* __restrict__ Vtb, float* __restrict__ outK, float* __restrict__ outV) {
  const int K = 4096;
  __shared__ unsigned short As[4096];
  __shared__ unsigned short Bs[4096];
  const int tid = threadIdx.x;
  const int wave = tid >> 6, lane = tid & 63;
  const int g = lane >> 4, l15 = lane & 15;
  // bijective XCD swizzle (nwg=1536, 1536%8==0): each XCD gets 192 consecutive tiles
  const int flat = blockIdx.x + gridDim.x * blockIdx.y;
  const int swz = (flat & 7) * 192 + (flat >> 3);
  const int bm = swz & 31, bn = swz >> 5;
  const int wr = wave >> 1, wc = wave & 1;

  const int slot0 = wave * 128 + lane, slot1 = slot0 + 64;
  const int r0 = slot0 >> 2, c0 = (slot0 & 3) ^ ((r0 >> 1) & 3);
  const int r1 = slot1 >> 2, c1 = (slot1 & 3) ^ ((r1 >> 1) & 3);

  const unsigned short* Ab = Xb + bm * 128 * K;
  const unsigned short* Bb = Wb + bn * 128 * K;
  const unsigned short* gA0 = Ab + r0 * K + c0 * 8;
  const unsigned short* gA1 = Ab + r1 * K + c1 * 8;
  const unsigned short* gB0 = Bb + r0 * K + c0 * 8;
  const unsigned short* gB1 = Bb + r1 * K + c1 * 8;
  unsigned short* ldsA0 = As + wave * 1024;
  unsigned short* ldsA1 = As + wave * 1024 + 512;
  unsigned short* ldsB0 = Bs + wave * 1024;
  unsigned short* ldsB1 = Bs + wave * 1024 + 512;

  f32x4 acc[4][4] = {};

  for (int k0 = 0; k0 < K; k0 += 32) {
    async16(ldsA0, gA0 + k0);
    async16(ldsA1, gA1 + k0);
    async16(ldsB0, gB0 + k0);
    async16(ldsB1, gB1 + k0);
    __syncthreads();
    bf16x8 af[4], bfr[4];
#pragma unroll
    for (int i = 0; i < 4; i++) {
      const int rm = wr * 64 + i * 16 + l15;
      af[i] = *(const bf16x8*)(As + rm * 32 + ((g ^ ((rm >> 1) & 3)) * 8));
      const int rn = wc * 64 + i * 16 + l15;
      bfr[i] = *(const bf16x8*)(Bs + rn * 32 + ((g ^ ((rn >> 1) & 3)) * 8));
    }
#pragma unroll
    for (int i = 0; i < 4; i++)
#pragma unroll
      for (int j = 0; j < 4; j++)
        acc[i][j] = __builtin_amdgcn_mfma_f32_16x16x32_bf16(af[i], bfr[j], acc[i][j], 0, 0, 0);
    __syncthreads();
  }

  const int b = bm >> 3;
  const int qbase = (bm & 7) << 7;
  if (bn < 32) {  // q heads -> Qb bf16
#pragma unroll
    for (int j = 0; j < 4; j++) {
      const int n = bn * 128 + wc * 64 + j * 16 + l15;
      const float bv = bias[n];
      const int h = n >> 7, d = n & 127;
#pragma unroll
      for (int i = 0; i < 4; i++) {
        const int q0 = qbase + wr * 64 + i * 16 + g * 4;
        unsigned short* dst = Qb + (((b * 32 + h) * 1024 + q0) * 128 + d);
#pragma unroll
        for (int r = 0; r < 4; r++) dst[r * 128] = f2bf(acc[i][j][r] + bv);
      }
    }
  } else if (bn < 40) {  // k_new -> outK fp32 + Kb bf16
#pragma unroll
    for (int j = 0; j < 4; j++) {
      const int n = bn * 128 + wc * 64 + j * 16 + l15;
      const float bv = bias[n];
      const int n2 = n - 4096, kv = n2 >> 7, d = n2 & 127;
#pragma unroll
      for (int i = 0; i < 4; i++) {
        const int q0 = qbase + wr * 64 + i * 16 + g * 4;
        float* ko = outK + (((b * 2048 + 1024 + q0) * 8 + kv) * 128 + d);
        unsigned short* kb = Kb + (((b * 8 + kv) * 2048 + 1024 + q0) * 128 + d);
#pragma unroll
        for (int r = 0; r < 4; r++) {
          float v = acc[i][j][r] + bv;
          ko[r * 1024] = v;
          kb[r * 128] = f2bf(v);
        }
      }
    }
  } else {  // v_new -> outV fp32 + Vtb bf16 (transposed)
#pragma unroll
    for (int j = 0; j < 4; j++) {
      const int n = bn * 128 + wc * 64 + j * 16 + l15;
      const float bv = bias[n];
      const int n2 = n - 5120, kv = n2 >> 7, d = n2 & 127;
#pragma unroll
      for (int i = 0; i < 4; i++) {
        const int q0 = qbase + wr * 64 + i * 16 + g * 4;
        float* vo = outV + (((b * 2048 + 1024 + q0) * 8 + kv) * 128 + d);
        u16x4 pk;
#pragma unroll
        for (int r = 0; r < 4; r++) {
          float v = acc[i][j][r] + bv;
          vo[r * 1024] = v;
          pk[r] = f2bf(v);
        }
        *(u16x4*)(Vtb + ((b * 8 + kv) * 128 + d) * 2048 + 1024 + q0) = pk;
      }
    }
  }
}

// ---------------- flash attention (v2: swapped QK^T, in-register softmax) ----
// grid (qt=8, h=32, b=4); 4 waves x 32 q = 128 q/block; KVBLK=64.
// Swapped QK: ST = mfma(K_frag, Q_frag) -> out col = q = lane&15, row s = 4g+r.
// Each lane owns q=l15's scores for s = st*16+4g+r (16 values) -> softmax is
// 15 fmax/adds in-register + 2 shfl_xor (lanes l15, l15+16, +32, +48).
// P bounced through wave-private LDS slab (stride 80 rows), no barrier.
// K LDS [64 s][128 d]: 16B chunks, chunk c at c^(s&7).
// V LDS [128 d][64 s]: 16B chunks, chunk c at c^(d&7).
__global__ __launch_bounds__(256) void attn_kernel(
    const unsigned short* __restrict__ Qb, const unsigned short* __restrict__ Kb,
    const unsigned short* __restrict__ Vtb, const float* __restrict__ mask,
    float* __restrict__ outO) {
  __shared__ unsigned short Ks[64 * 128];   // 16 KB
  __shared__ unsigned short Vs[128 * 64];   // 16 KB
  __shared__ unsigned short Ps[4][32 * 80]; // 20 KB, wave-private slabs

  const int tid = threadIdx.x, wave = tid >> 6, lane = tid & 63;
  const int g = lane >> 4, l15 = lane & 15;
  const int qt = blockIdx.x, h = blockIdx.y, b = blockIdx.z;
  const int kvh = h >> 2;

  const unsigned short* Kg = Kb + (b * 8 + kvh) * 2048 * 128;
  const unsigned short* Vg = Vtb + (b * 8 + kvh) * 128 * 2048;
  const int qg0 = qt * 128 + wave * 32;

  // Q B-fragments: col q = i*16+l15, k = d = kg*32+g*8..+7
  bf16x8 qf[2][4];
#pragma unroll
  for (int i = 0; i < 2; i++) {
    const unsigned short* qrow = Qb + (((b * 32 + h) * 1024) + qg0 + i * 16 + l15) * 128;
#pragma unroll
    for (int kg = 0; kg < 4; kg++) qf[i][kg] = *(const bf16x8*)(qrow + kg * 32 + g * 8);
  }

  f32x4 acc_o[2][8] = {};
  float m_run[2] = {-1e30f, -1e30f}, l_run[2] = {0.f, 0.f};

  unsigned short* Pw = Ps[wave];
  const int sbB = (lane & 48) | (g << 2);  // broadcast src base: l15 = 4g

  for (int s0 = 0; s0 < 2048; s0 += 64) {
    __syncthreads();  // prev tile fully consumed
#pragma unroll
    for (int j = 0; j < 4; j++) {
      // K: 1024 slots of 16B; slot -> row r=slot>>4, pos p=slot&15, src chunk p^(r&7)
      const int ksl = (j * 4 + wave) * 64 + lane;
      const int kr = ksl >> 4, kp = ksl & 15;
      async16(Ks + (j * 4 + wave) * 512, Kg + (s0 + kr) * 128 + ((kp ^ (kr & 7)) * 8));
      // V: slot -> row d=slot>>3, pos p=slot&7, src chunk p^(d&7)
      const int vd = ksl >> 3, vp = ksl & 7;
      async16(Vs + (j * 4 + wave) * 512, Vg + vd * 2048 + s0 + ((vp ^ (vd & 7)) * 8));
    }
    __syncthreads();  // staging complete (vmcnt drained by barrier)

    // --- QK^T (swapped): scv[i][st] = ST[s=st*16+4g+r, q=i*16+l15]
    f32x4 scv[2][4];
#pragma unroll
    for (int st = 0; st < 4; st++) {
      bf16x8 kfr[4];
      const int row = st * 16 + l15;
#pragma unroll
      for (int kg = 0; kg < 4; kg++)
        kfr[kg] = *(const bf16x8*)(Ks + row * 128 + (((kg * 4 + g) ^ (row & 7)) * 8));
#pragma unroll
      for (int i = 0; i < 2; i++) {
        f32x4 a = {};
#pragma unroll
        for (int kg = 0; kg < 4; kg++)
          a = __builtin_amdgcn_mfma_f32_16x16x32_bf16(kfr[kg], qf[i][kg], a, 0, 0, 0);
        scv[i][st] = a;
      }
    }

    // --- online softmax (log2 domain), P -> wave-private LDS
    float alpha_bc[2][4];
#pragma unroll
    for (int i = 0; i < 2; i++) {
      const float* mrow = mask + ((b * 1024 + qg0 + i * 16 + l15) * 2048) + s0;
      f32x4 x[4];
#pragma unroll
      for (int st = 0; st < 4; st++) {
        const f32x4 mv = *(const f32x4*)(mrow + st * 16 + g * 4);
#pragma unroll
        for (int r = 0; r < 4; r++) x[st][r] = scv[i][st][r] * SCALE2 + mv[r] * LOG2E;
      }
      float mx = x[0][0];
#pragma unroll
      for (int st = 0; st < 4; st++)
#pragma unroll
        for (int r = 0; r < 4; r++) mx = fmaxf(mx, x[st][r]);
      mx = fmaxf(mx, __shfl_xor(mx, 16));
      mx = fmaxf(mx, __shfl_xor(mx, 32));
      const float mnew = fmaxf(m_run[i], mx);
      const float al = exp2f(m_run[i] - mnew);
      m_run[i] = mnew;
      float ps = 0.f;
#pragma unroll
      for (int st = 0; st < 4; st++) {
        u16x4 pk;
#pragma unroll
        for (int r = 0; r < 4; r++) {
          const float p = exp2f(x[st][r] - mnew);
          ps += p;
          pk[r] = f2bf(p);
        }
        *(u16x4*)(Pw + (i * 16 + l15) * 80 + st * 16 + g * 4) = pk;
      }
      ps += __shfl_xor(ps, 16);
      ps += __shfl_xor(ps, 32);
      l_run[i] = l_run[i] * al + ps;
      // broadcast alpha from softmax domain (q=l15) to acc rows (q=4g+r)
#pragma unroll
      for (int r = 0; r < 4; r++) alpha_bc[i][r] = __shfl(al, sbB + r);
    }

    // --- rescale O
#pragma unroll
    for (int i = 0; i < 2; i++)
#pragma unroll
      for (int ds = 0; ds < 8; ds++)
#pragma unroll
        for (int r = 0; r < 4; r++) acc_o[i][ds][r] *= alpha_bc[i][r];

    // --- PV: out[q,d] += P[q,s] V[s,d]; A=P (row q=l15), B=V^T (col d=l15)
    bf16x8 pf[2][2];
#pragma unroll
    for (int i = 0; i < 2; i++)
#pragma unroll
      for (int ks = 0; ks < 2; ks++)
        pf[i][ks] = *(const bf16x8*)(Pw + (i * 16 + l15) * 80 + ks * 32 + g * 8);
#pragma unroll
    for (int ds = 0; ds < 8; ds++) {
      const int dr = ds * 16 + l15;
#pragma unroll
      for (int ks = 0; ks < 2; ks++) {
        bf16x8 vf = *(const bf16x8*)(Vs + dr * 64 + (((ks * 4 + g) ^ (dr & 7)) * 8));
#pragma unroll
        for (int i = 0; i < 2; i++)
          acc_o[i][ds] = __builtin_amdgcn_mfma_f32_16x16x32_bf16(pf[i][ks], vf, acc_o[i][ds], 0, 0, 0);
      }
    }
  }

  // epilogue: out[b][h][q][d] fp32; acc rows q = i*16+4g+r, cols d = ds*16+l15
#pragma unroll
  for (int i = 0; i < 2; i++) {
    const float invl = 1.0f / l_run[i];
#pragma unroll
    for (int r = 0; r < 4; r++) {
      const float inv = __shfl(invl, sbB + r);
      const int qgl = qg0 + i * 16 + g * 4 + r;
      float* orow = outO + (((b * 32 + h) * 1024) + qgl) * 128 + l15;
#pragma unroll
      for (int ds = 0; ds < 8; ds++) orow[ds * 16] = acc_o[i][ds][r] * inv;
    }
  }
}

// ---------------- launcher ----------------

extern "C" void kernel_launch(void* const* d_in, const int* in_sizes, int n_in,
                              void* d_out, int out_size, void* d_ws, size_t ws_size,
                              hipStream_t stream) {
  const float* input_t = (const float*)d_in[0];
  const float* key_cache = (const float*)d_in[1];
  const float* value_cache = (const float*)d_in[2];
  const float* attn_mask = (const float*)d_in[4];
  const float* qkv_w = (const float*)d_in[6];
  const float* qkv_b = (const float*)d_in[7];

  float* out = (float*)d_out;                 // [4][32][1024][128]
  float* outK = out + 16777216;               // [4][2048][8][128]
  float* outV = outK + 8388608;               // [4][2048][8][128]

  char* ws = (char*)d_ws;                     // needs 150994944 B
  unsigned short* Xb = (unsigned short*)ws;
  unsigned short* Wb = (unsigned short*)(ws + 33554432);
  unsigned short* Qb = (unsigned short*)(ws + 83886080);
  unsigned short* Kb = (unsigned short*)(ws + 117440512);
  unsigned short* Vtb = (unsigned short*)(ws + 134217728);

  hipLaunchKernelGGL(conv_bf16_kernel, dim3(8192), dim3(256), 0, stream, input_t, Xb, 2097152);
  hipLaunchKernelGGL(conv_bf16_kernel, dim3(12288), dim3(256), 0, stream, qkv_w, Wb, 3145728);
  hipLaunchKernelGGL(conv_k_kernel, dim3(2048), dim3(256), 0, stream, key_cache, Kb, outK);
  hipLaunchKernelGGL(conv_v_kernel, dim3(4096), dim3(256), 0, stream, value_cache, Vtb, outV);
  hipLaunchKernelGGL(qkv_gemm_kernel, dim3(32, 48), dim3(256), 0, stream,
                     Xb, Wb, qkv_b, Qb, Kb, Vtb, outK, outV);
  hipLaunchKernelGGL(attn_kernel, dim3(8, 32, 4), dim3(256), 0, stream,
                     Qb, Kb, Vtb, attn_mask, out);
}

// Round 6
// 928.604 us; speedup vs baseline: 1.3701x; 1.1970x over previous
//
#include <hip/hip_runtime.h>

// MaskedMHA: fused QKV GEMM + GQA flash attention, MI355X gfx950.
// B=4, Q=1024, P=1024, S=2048, H=32, KV=8, D=128, HID=4096, N_qkv=6144.
// ws layout (needs 144 MiB):
//   Xb  [4096][4096] bf16 @ 0          (32 MiB)
//   Wb  [6144][4096] bf16 @ 33554432   (48 MiB)
//   Qb  [B][H][Q][D] bf16 @ 83886080   (32 MiB)
//   Kb  [B][KV][S][D] bf16 @ 117440512 (16 MiB)
//   Vtb [B][KV][D][S] bf16 @ 134217728 (16 MiB)  (V pre-transposed)
// d_out: out fp32 [B][H][Q][D] | k fp32 [B][S][KV][D] | v fp32 [B][S][KV][D]

typedef __attribute__((ext_vector_type(4))) float f32x4;
typedef __attribute__((ext_vector_type(8))) short bf16x8;
typedef __attribute__((ext_vector_type(8))) unsigned short u16x8;
typedef __attribute__((ext_vector_type(4))) unsigned short u16x4;
typedef __attribute__((ext_vector_type(4))) unsigned int u32x4;

#define LOG2E 1.4426950408889634f
#define SCALE2 0.12751649736689687f  /* (1/sqrt(128)) * LOG2E */

__device__ __forceinline__ unsigned short f2bf(float f) {
  unsigned int u = __builtin_bit_cast(unsigned int, f);
  u = (u + 0x7FFFu + ((u >> 16) & 1u)) >> 16;  // RNE
  return (unsigned short)u;
}

__device__ __forceinline__ int cvtpk_bf16(float lo, float hi) {
  int d;
  asm("v_cvt_pk_bf16_f32 %0, %1, %2" : "=v"(d) : "v"(lo), "v"(hi));
  return d;
}

// async global->LDS, 16B per lane. LDS dest is wave-uniform base + lane*16.
__device__ __forceinline__ void async16(void* lds, const void* g) {
  __builtin_amdgcn_global_load_lds(
      (const __attribute__((address_space(1))) unsigned int*)(unsigned long long)g,
      (__attribute__((address_space(3))) unsigned int*)(unsigned int)(unsigned long long)lds,
      16, 0, 0);
}

// ---------------- converters ----------------

__global__ __launch_bounds__(256) void conv_bf16_kernel(
    const float* __restrict__ in, unsigned short* __restrict__ out, int n8) {
  int i = blockIdx.x * 256 + threadIdx.x;
  if (i >= n8) return;
  const f32x4* in4 = (const f32x4*)in;
  f32x4 a = in4[i * 2], c = in4[i * 2 + 1];
  u16x8 o;
#pragma unroll
  for (int j = 0; j < 4; j++) { o[j] = f2bf(a[j]); o[4 + j] = f2bf(c[j]); }
  *(u16x8*)(out + i * 8) = o;
}

// key_cache [B,1024,KV,D] -> Kb bf16 [B,KV,2048,D] (s<1024) + outK fp32 copy
__global__ __launch_bounds__(256) void conv_k_kernel(
    const float* __restrict__ kc, unsigned short* __restrict__ Kb, float* __restrict__ outK) {
  int i = blockIdx.x * 256 + threadIdx.x;  // 524288 total (8 elems each)
  int d8 = i & 15, kv = (i >> 4) & 7, s = (i >> 7) & 1023, b = i >> 17;
  const float* src = kc + (((b * 1024 + s) * 8 + kv) * 128) + d8 * 8;
  f32x4 v0 = ((const f32x4*)src)[0], v1 = ((const f32x4*)src)[1];
  float* ko = outK + (((b * 2048 + s) * 8 + kv) * 128) + d8 * 8;
  ((f32x4*)ko)[0] = v0; ((f32x4*)ko)[1] = v1;
  u16x8 o;
#pragma unroll
  for (int j = 0; j < 4; j++) { o[j] = f2bf(v0[j]); o[4 + j] = f2bf(v1[j]); }
  *(u16x8*)(Kb + ((b * 8 + kv) * 2048 + s) * 128 + d8 * 8) = o;
}

// value_cache [B,1024,KV,D] -> Vtb bf16 [B,KV,D,2048] (transpose, s<1024) + outV fp32 copy
__global__ __launch_bounds__(256) void conv_v_kernel(
    const float* __restrict__ vc, unsigned short* __restrict__ Vtb, float* __restrict__ outV) {
  __shared__ unsigned short t[32][33];
  const int bid = blockIdx.x;                 // 4096 blocks
  const int s0 = (bid & 31) * 32;
  const int d0 = ((bid >> 5) & 3) * 32;
  const int kv = (bid >> 7) & 7;
  const int b = bid >> 10;
  const int tx = threadIdx.x & 31, ty = threadIdx.x >> 5;
#pragma unroll
  for (int p = 0; p < 4; p++) {
    const int si = p * 8 + ty;
    float v = vc[(((b * 1024 + s0 + si) * 8 + kv) * 128) + d0 + tx];
    outV[(((b * 2048 + s0 + si) * 8 + kv) * 128) + d0 + tx] = v;
    t[tx][si] = f2bf(v);
  }
  __syncthreads();
#pragma unroll
  for (int p = 0; p < 4; p++) {
    const int dr = p * 8 + ty;
    Vtb[((b * 8 + kv) * 128 + d0 + dr) * 2048 + s0 + tx] = t[dr][tx];
  }
}

// ---------------- QKV GEMM ----------------
// C[m,n] = sum_k Xb[m,k]*Wb[n,k] + bias[n]; 128x128 tile, BK=32, 4 waves.
// LDS rows 64B = 4 x 16B chunks; chunk c stored at c ^ ((row>>1)&3).
__global__ __launch_bounds__(256) void qkv_gemm_kernel(
    const unsigned short* __restrict__ Xb, const unsigned short* __restrict__ Wb,
    const float* __restrict__ bias,
    unsigned short* __restrict__ Qb, unsigned short* __restrict__ Kb,
    unsigned short* __restrict__ Vtb, float* __restrict__ outK, float* __restrict__ outV) {
  const int K = 4096;
  __shared__ unsigned short As[4096];
  __shared__ unsigned short Bs[4096];
  const int tid = threadIdx.x;
  const int wave = tid >> 6, lane = tid & 63;
  const int g = lane >> 4, l15 = lane & 15;
  // bijective XCD swizzle (nwg=1536, 1536%8==0): each XCD gets 192 consecutive tiles
  const int flat = blockIdx.x + gridDim.x * blockIdx.y;
  const int swz = (flat & 7) * 192 + (flat >> 3);
  const int bm = swz & 31, bn = swz >> 5;
  const int wr = wave >> 1, wc = wave & 1;

  const int slot0 = wave * 128 + lane, slot1 = slot0 + 64;
  const int r0 = slot0 >> 2, c0 = (slot0 & 3) ^ ((r0 >> 1) & 3);
  const int r1 = slot1 >> 2, c1 = (slot1 & 3) ^ ((r1 >> 1) & 3);

  const unsigned short* Ab = Xb + bm * 128 * K;
  const unsigned short* Bb = Wb + bn * 128 * K;
  const unsigned short* gA0 = Ab + r0 * K + c0 * 8;
  const unsigned short* gA1 = Ab + r1 * K + c1 * 8;
  const unsigned short* gB0 = Bb + r0 * K + c0 * 8;
  const unsigned short* gB1 = Bb + r1 * K + c1 * 8;
  unsigned short* ldsA0 = As + wave * 1024;
  unsigned short* ldsA1 = As + wave * 1024 + 512;
  unsigned short* ldsB0 = Bs + wave * 1024;
  unsigned short* ldsB1 = Bs + wave * 1024 + 512;

  f32x4 acc[4][4] = {};

  for (int k0 = 0; k0 < K; k0 += 32) {
    async16(ldsA0, gA0 + k0);
    async16(ldsA1, gA1 + k0);
    async16(ldsB0, gB0 + k0);
    async16(ldsB1, gB1 + k0);
    __syncthreads();
    bf16x8 af[4], bfr[4];
#pragma unroll
    for (int i = 0; i < 4; i++) {
      const int rm = wr * 64 + i * 16 + l15;
      af[i] = *(const bf16x8*)(As + rm * 32 + ((g ^ ((rm >> 1) & 3)) * 8));
      const int rn = wc * 64 + i * 16 + l15;
      bfr[i] = *(const bf16x8*)(Bs + rn * 32 + ((g ^ ((rn >> 1) & 3)) * 8));
    }
#pragma unroll
    for (int i = 0; i < 4; i++)
#pragma unroll
      for (int j = 0; j < 4; j++)
        acc[i][j] = __builtin_amdgcn_mfma_f32_16x16x32_bf16(af[i], bfr[j], acc[i][j], 0, 0, 0);
    __syncthreads();
  }

  const int b = bm >> 3;
  const int qbase = (bm & 7) << 7;
  if (bn < 32) {  // q heads -> Qb bf16
#pragma unroll
    for (int j = 0; j < 4; j++) {
      const int n = bn * 128 + wc * 64 + j * 16 + l15;
      const float bv = bias[n];
      const int h = n >> 7, d = n & 127;
#pragma unroll
      for (int i = 0; i < 4; i++) {
        const int q0 = qbase + wr * 64 + i * 16 + g * 4;
        unsigned short* dst = Qb + (((b * 32 + h) * 1024 + q0) * 128 + d);
#pragma unroll
        for (int r = 0; r < 4; r++) dst[r * 128] = f2bf(acc[i][j][r] + bv);
      }
    }
  } else if (bn < 40) {  // k_new -> outK fp32 + Kb bf16
#pragma unroll
    for (int j = 0; j < 4; j++) {
      const int n = bn * 128 + wc * 64 + j * 16 + l15;
      const float bv = bias[n];
      const int n2 = n - 4096, kv = n2 >> 7, d = n2 & 127;
#pragma unroll
      for (int i = 0; i < 4; i++) {
        const int q0 = qbase + wr * 64 + i * 16 + g * 4;
        float* ko = outK + (((b * 2048 + 1024 + q0) * 8 + kv) * 128 + d);
        unsigned short* kb = Kb + (((b * 8 + kv) * 2048 + 1024 + q0) * 128 + d);
#pragma unroll
        for (int r = 0; r < 4; r++) {
          float v = acc[i][j][r] + bv;
          ko[r * 1024] = v;
          kb[r * 128] = f2bf(v);
        }
      }
    }
  } else {  // v_new -> outV fp32 + Vtb bf16 (transposed)
#pragma unroll
    for (int j = 0; j < 4; j++) {
      const int n = bn * 128 + wc * 64 + j * 16 + l15;
      const float bv = bias[n];
      const int n2 = n - 5120, kv = n2 >> 7, d = n2 & 127;
#pragma unroll
      for (int i = 0; i < 4; i++) {
        const int q0 = qbase + wr * 64 + i * 16 + g * 4;
        float* vo = outV + (((b * 2048 + 1024 + q0) * 8 + kv) * 128 + d);
        u16x4 pk;
#pragma unroll
        for (int r = 0; r < 4; r++) {
          float v = acc[i][j][r] + bv;
          vo[r * 1024] = v;
          pk[r] = f2bf(v);
        }
        *(u16x4*)(Vtb + ((b * 8 + kv) * 128 + d) * 2048 + 1024 + q0) = pk;
      }
    }
  }
}

// ---------------- flash attention (v3) ----------------
// 8 waves x 32 q = 256 q/block; grid (qt=4, h=32, b=4) = 512 blocks; KVBLK=64.
// Double-buffered K/V (64 KB), prefetch-before-compute, 1 barrier/tile (T3).
// Swapped QK (verified): scv[i][st][r] = S[q=i*16+l15][s=st*16+4g+r].
// P redistribution fully in-register: cvt_pk_bf16 pairs + ds_bpermute
//   pf[i][ks] dword w  =  pk[i][2ks+(g>>1)][w&1]  from lane l15+16*(2(g&1)+(w>>1)).
// Defer-max (T13): skip O-rescale when tile max <= m_run + 8 (wave-uniform).
__global__ __launch_bounds__(512, 2) void attn_kernel(
    const unsigned short* __restrict__ Qb, const unsigned short* __restrict__ Kb,
    const unsigned short* __restrict__ Vtb, const float* __restrict__ mask,
    float* __restrict__ outO) {
  __shared__ unsigned short Ks[2][8192];   // [64 s][128 d], chunk c at c^(s&7)
  __shared__ unsigned short Vs[2][8192];   // [128 d][64 s], chunk c at c^(d&7)

  const int tid = threadIdx.x, wave = tid >> 6, lane = tid & 63;
  const int g = lane >> 4, l15 = lane & 15;
  const int qt = blockIdx.x, h = blockIdx.y, b = blockIdx.z;
  const int kvh = h >> 2;

  const unsigned short* Kg = Kb + (b * 8 + kvh) * 2048 * 128;
  const unsigned short* Vg = Vtb + (b * 8 + kvh) * 128 * 2048;
  const int qg0 = qt * 256 + wave * 32;

  // Q B-fragments: col q = i*16+l15, k = d = kg*32+g*8..+7
  bf16x8 qf[2][4];
#pragma unroll
  for (int i = 0; i < 2; i++) {
    const unsigned short* qrow = Qb + (((b * 32 + h) * 1024) + qg0 + i * 16 + l15) * 128;
#pragma unroll
    for (int kg = 0; kg < 4; kg++) qf[i][kg] = *(const bf16x8*)(qrow + kg * 32 + g * 8);
  }

  f32x4 acc_o[2][8] = {};
  float m_run[2] = {-1e30f, -1e30f}, l_run[2] = {0.f, 0.f};

  const int sbB = (lane & 48) | (g << 2);            // alpha broadcast src base
  const int srcA4 = ((lane & 15) | ((lane & 16) << 1)) << 2;  // bpermute byte idx
  const int srcB4 = srcA4 + 64;
  const bool hi32 = (lane & 32) != 0;                // g>>1

  // prologue: stage tile 0 into buffer 0
  {
#pragma unroll
    for (int j = 0; j < 2; j++) {
      const int region = j * 8 + wave;
      const int slot = region * 64 + lane;
      const int kr = slot >> 4, kp = slot & 15;
      async16(&Ks[0][region * 512], Kg + kr * 128 + ((kp ^ (kr & 7)) * 8));
      const int vd = slot >> 3, vp = slot & 7;
      async16(&Vs[0][region * 512], Vg + vd * 2048 + ((vp ^ (vd & 7)) * 8));
    }
  }
  __syncthreads();

  for (int t = 0; t < 32; t++) {
    const int cb = t & 1;
    const unsigned short* Kc = Ks[cb];
    const unsigned short* Vc = Vs[cb];
    // prefetch next tile into other buffer (completes by the end-of-tile barrier)
    if (t < 31) {
      const int s1 = (t + 1) * 64;
#pragma unroll
      for (int j = 0; j < 2; j++) {
        const int region = j * 8 + wave;
        const int slot = region * 64 + lane;
        const int kr = slot >> 4, kp = slot & 15;
        async16(&Ks[cb ^ 1][region * 512], Kg + (s1 + kr) * 128 + ((kp ^ (kr & 7)) * 8));
        const int vd = slot >> 3, vp = slot & 7;
        async16(&Vs[cb ^ 1][region * 512], Vg + vd * 2048 + s1 + ((vp ^ (vd & 7)) * 8));
      }
    }
    const int s0 = t * 64;

    // --- QK^T (swapped): scv[i][st] = S[s=st*16+4g+r][q=i*16+l15]
    f32x4 scv[2][4];
#pragma unroll
    for (int st = 0; st < 4; st++) {
      bf16x8 kfr[4];
      const int row = st * 16 + l15;
#pragma unroll
      for (int kg = 0; kg < 4; kg++)
        kfr[kg] = *(const bf16x8*)(Kc + row * 128 + (((kg * 4 + g) ^ (row & 7)) * 8));
#pragma unroll
      for (int i = 0; i < 2; i++) {
        f32x4 a = {};
#pragma unroll
        for (int kg = 0; kg < 4; kg++)
          a = __builtin_amdgcn_mfma_f32_16x16x32_bf16(kfr[kg], qf[i][kg], a, 0, 0, 0);
        scv[i][st] = a;
      }
    }

    // --- online softmax (log2 domain), in-register
    float mx[2];
    f32x4 x[2][4];
#pragma unroll
    for (int i = 0; i < 2; i++) {
      const float* mrow = mask + ((b * 1024 + qg0 + i * 16 + l15) * 2048) + s0;
#pragma unroll
      for (int st = 0; st < 4; st++) {
        const f32x4 mv = *(const f32x4*)(mrow + st * 16 + g * 4);
#pragma unroll
        for (int r = 0; r < 4; r++) x[i][st][r] = scv[i][st][r] * SCALE2 + mv[r] * LOG2E;
      }
      float m0 = x[i][0][0];
#pragma unroll
      for (int st = 0; st < 4; st++)
#pragma unroll
        for (int r = 0; r < 4; r++) m0 = fmaxf(m0, x[i][st][r]);
      m0 = fmaxf(m0, __shfl_xor(m0, 16));
      m0 = fmaxf(m0, __shfl_xor(m0, 32));
      mx[i] = m0;
    }

    const int skip = __all((mx[0] <= m_run[0] + 8.0f) & (mx[1] <= m_run[1] + 8.0f));

    int pk[2][4][2];  // [i][st][h] packed bf16 pairs of P
#pragma unroll
    for (int i = 0; i < 2; i++) {
      float mnew = m_run[i], al = 1.0f;
      if (!skip) {
        mnew = fmaxf(m_run[i], mx[i]);
        al = exp2f(m_run[i] - mnew);
        m_run[i] = mnew;
      }
      float ps = 0.f;
#pragma unroll
      for (int st = 0; st < 4; st++) {
        float p0 = exp2f(x[i][st][0] - mnew);
        float p1 = exp2f(x[i][st][1] - mnew);
        float p2 = exp2f(x[i][st][2] - mnew);
        float p3 = exp2f(x[i][st][3] - mnew);
        ps += (p0 + p1) + (p2 + p3);
        pk[i][st][0] = cvtpk_bf16(p0, p1);
        pk[i][st][1] = cvtpk_bf16(p2, p3);
      }
      ps += __shfl_xor(ps, 16);
      ps += __shfl_xor(ps, 32);
      l_run[i] = l_run[i] * al + ps;
      if (!skip) {
#pragma unroll
        for (int r = 0; r < 4; r++) {
          const float ab = __shfl(al, sbB + r);
#pragma unroll
          for (int ds = 0; ds < 8; ds++) acc_o[i][ds][r] *= ab;
        }
      }
    }

    // --- P redistribution: build PV A-fragments in-register via bpermute
    bf16x8 pf[2][2];
#pragma unroll
    for (int i = 0; i < 2; i++)
#pragma unroll
      for (int ks = 0; ks < 2; ks++) {
        const int a0 = __builtin_amdgcn_ds_bpermute(srcA4, pk[i][2 * ks][0]);
        const int b0 = __builtin_amdgcn_ds_bpermute(srcA4, pk[i][2 * ks + 1][0]);
        const int a1 = __builtin_amdgcn_ds_bpermute(srcA4, pk[i][2 * ks][1]);
        const int b1 = __builtin_amdgcn_ds_bpermute(srcA4, pk[i][2 * ks + 1][1]);
        const int a2 = __builtin_amdgcn_ds_bpermute(srcB4, pk[i][2 * ks][0]);
        const int b2 = __builtin_amdgcn_ds_bpermute(srcB4, pk[i][2 * ks + 1][0]);
        const int a3 = __builtin_amdgcn_ds_bpermute(srcB4, pk[i][2 * ks][1]);
        const int b3 = __builtin_amdgcn_ds_bpermute(srcB4, pk[i][2 * ks + 1][1]);
        u32x4 dw;
        dw[0] = (unsigned)(hi32 ? b0 : a0);
        dw[1] = (unsigned)(hi32 ? b1 : a1);
        dw[2] = (unsigned)(hi32 ? b2 : a2);
        dw[3] = (unsigned)(hi32 ? b3 : a3);
        pf[i][ks] = __builtin_bit_cast(bf16x8, dw);
      }

    // --- PV: out[q,d] += P[q,s] V[s,d]; A=P (row q=l15), B=V^T (col d=l15)
#pragma unroll
    for (int ds = 0; ds < 8; ds++) {
      const int dr = ds * 16 + l15;
#pragma unroll
      for (int ks = 0; ks < 2; ks++) {
        bf16x8 vf = *(const bf16x8*)(Vc + dr * 64 + (((ks * 4 + g) ^ (dr & 7)) * 8));
#pragma unroll
        for (int i = 0; i < 2; i++)
          acc_o[i][ds] = __builtin_amdgcn_mfma_f32_16x16x32_bf16(pf[i][ks], vf, acc_o[i][ds], 0, 0, 0);
      }
    }

    __syncthreads();  // drains prefetch vmcnt + guards buffer swap
  }

  // epilogue: out[b][h][q][d] fp32; acc rows q = i*16+4g+r, cols d = ds*16+l15
#pragma unroll
  for (int i = 0; i < 2; i++) {
    const float invl = 1.0f / l_run[i];
#pragma unroll
    for (int r = 0; r < 4; r++) {
      const float inv = __shfl(invl, sbB + r);
      const int qgl = qg0 + i * 16 + g * 4 + r;
      float* orow = outO + (((b * 32 + h) * 1024) + qgl) * 128 + l15;
#pragma unroll
      for (int ds = 0; ds < 8; ds++) orow[ds * 16] = acc_o[i][ds][r] * inv;
    }
  }
}

// ---------------- launcher ----------------

extern "C" void kernel_launch(void* const* d_in, const int* in_sizes, int n_in,
                              void* d_out, int out_size, void* d_ws, size_t ws_size,
                              hipStream_t stream) {
  const float* input_t = (const float*)d_in[0];
  const float* key_cache = (const float*)d_in[1];
  const float* value_cache = (const float*)d_in[2];
  const float* attn_mask = (const float*)d_in[4];
  const float* qkv_w = (const float*)d_in[6];
  const float* qkv_b = (const float*)d_in[7];

  float* out = (float*)d_out;                 // [4][32][1024][128]
  float* outK = out + 16777216;               // [4][2048][8][128]
  float* outV = outK + 8388608;               // [4][2048][8][128]

  char* ws = (char*)d_ws;                     // needs 150994944 B
  unsigned short* Xb = (unsigned short*)ws;
  unsigned short* Wb = (unsigned short*)(ws + 33554432);
  unsigned short* Qb = (unsigned short*)(ws + 83886080);
  unsigned short* Kb = (unsigned short*)(ws + 117440512);
  unsigned short* Vtb = (unsigned short*)(ws + 134217728);

  hipLaunchKernelGGL(conv_bf16_kernel, dim3(8192), dim3(256), 0, stream, input_t, Xb, 2097152);
  hipLaunchKernelGGL(conv_bf16_kernel, dim3(12288), dim3(256), 0, stream, qkv_w, Wb, 3145728);
  hipLaunchKernelGGL(conv_k_kernel, dim3(2048), dim3(256), 0, stream, key_cache, Kb, outK);
  hipLaunchKernelGGL(conv_v_kernel, dim3(4096), dim3(256), 0, stream, value_cache, Vtb, outV);
  hipLaunchKernelGGL(qkv_gemm_kernel, dim3(32, 48), dim3(256), 0, stream,
                     Xb, Wb, qkv_b, Qb, Kb, Vtb, outK, outV);
  hipLaunchKernelGGL(attn_kernel, dim3(4, 32, 4), dim3(512), 0, stream,
                     Qb, Kb, Vtb, attn_mask, out);
}